// Round 2
// baseline (3234.300 us; speedup 1.0000x reference)
//
#include <hip/hip_runtime.h>
#include <math.h>

#define BB 32
#define DD 64
#define HH 8
#define NNN 4096
#define LL 12
#define PP (NNN * LL)            // 49152 positions per (b, channel)

// pass_a geometry: 512-thread blocks, 64-pos tiles, exact-fill grid (4 blocks/CU)
#define NTILES_A 24
#define CHUNK_A (64 * NTILES_A)  // 1536
#define NCHUNK_A (PP / CHUNK_A)  // 32

// pass_b geometry: 256-thread blocks, 64-pos tiles, 8 blocks/CU resident
#define NTILES_B 12
#define CHUNK_B (64 * NTILES_B)  // 768
#define NCHUNK_B (PP / CHUNK_B)  // 64

#define VSTRIDE 68               // LDS row stride (floats): 16B-aligned rows, bank-skewed
#define SCALE 0.35355339059327373f

// ---------------------------------------------------------------------------
// prep: transpose the three 64x64 weight matrices into [c][o] layout in ws.
// Weight reads in the main passes are wave-uniform -> served via scalar path.
// ---------------------------------------------------------------------------
__global__ void prep(const float* __restrict__ wq, const float* __restrict__ wv,
                     const float* __restrict__ wc, float* __restrict__ wt)
{
    const int i = blockIdx.x * 256 + threadIdx.x;  // i = o*64 + c, 0..4095
    const int o = i >> 6, c = i & 63;
    wt[c * 64 + o]        = wq[i];
    wt[4096 + c * 64 + o] = wv[i];
    wt[8192 + c * 64 + o] = wc[i];
}

// ---------------------------------------------------------------------------
// Pass A: kv[b,l,h,x,y] = sum_n softmax(mem[h,l,n,:]*s)[x] * relu(Wv x + bv)[h*8+y]
// 512 threads: stage 1 = 8 channels/thread (wave-uniform og), stage 2 = 768
// (l,h,x) jobs mapped {t, 512+t}.  4 blocks/CU x 8 waves = 32 waves/CU.
// ---------------------------------------------------------------------------
__global__ __launch_bounds__(512, 8)
void pass_a(const float* __restrict__ x, const float* __restrict__ wvt,
            const float* __restrict__ bv, const float* __restrict__ mem,
            float* __restrict__ kv)
{
    __shared__ float v_tile[64 * VSTRIDE];   // [p][o]
    __shared__ float ks_tile[64 * VSTRIDE];  // [p][h*8+x]

    const int t = threadIdx.x;
    const int b = blockIdx.y;
    const int chunk0 = blockIdx.x * CHUNK_A;

    // stage-1 mapping: p1 = position-in-tile, og = 8-channel group (wave-uniform)
    const int p1 = t & 63;
    const int og = t >> 6;           // 0..7, constant within a 64-lane wave
    const int o0 = og << 3;
    const int o0u = __builtin_amdgcn_readfirstlane(o0);
    const float* __restrict__ wvu = wvt + o0u;

    float bvl[8];
#pragma unroll
    for (int j = 0; j < 8; j++) bvl[j] = bv[o0 + j];

    // stage-2 mapping: job j in 0..767 -> l = j>>6, h = (j>>3)&7, x = j&7
    // thread t owns job t, and job 512+t when t < 256
    const int h2 = (t >> 3) & 7;
    const int x2 = t & 7;
    const int l0 = t >> 6;           // 0..7, wave-uniform
    const int l1 = 8 + (t >> 6);     // 8..11 (valid only for t < 256)
    const bool has2 = (t < 256);

    float acc[2][8];
#pragma unroll
    for (int q = 0; q < 2; q++)
#pragma unroll
        for (int y = 0; y < 8; y++) acc[q][y] = 0.f;

    const float* xb = x + (size_t)(b * 64) * PP;

    for (int tile = 0; tile < NTILES_A; tile++) {
        const int pbase = chunk0 + tile * 64;

        // ---- key-softmax staging: 64 pos x 8 heads = 512 jobs, 1 per thread
        {
            int pos = t >> 3, h = t & 7;
            int pg = pbase + pos;
            int n = pg / 12;
            int l = pg - n * 12;
            const float4* mp = (const float4*)(mem + (((size_t)(h * 12 + l) * NNN + n) << 3));
            float4 a0 = mp[0], a1 = mp[1];
            float v0 = a0.x * SCALE, v1 = a0.y * SCALE, v2 = a0.z * SCALE, v3 = a0.w * SCALE;
            float v4 = a1.x * SCALE, v5 = a1.y * SCALE, v6 = a1.z * SCALE, v7 = a1.w * SCALE;
            float m = fmaxf(fmaxf(fmaxf(v0, v1), fmaxf(v2, v3)),
                            fmaxf(fmaxf(v4, v5), fmaxf(v6, v7)));
            float e0 = __expf(v0 - m), e1 = __expf(v1 - m), e2 = __expf(v2 - m), e3 = __expf(v3 - m);
            float e4 = __expf(v4 - m), e5 = __expf(v5 - m), e6 = __expf(v6 - m), e7 = __expf(v7 - m);
            float inv = 1.0f / (e0 + e1 + e2 + e3 + e4 + e5 + e6 + e7);
            float4* kp = (float4*)(ks_tile + pos * VSTRIDE + (h << 3));
            kp[0] = make_float4(e0 * inv, e1 * inv, e2 * inv, e3 * inv);
            kp[1] = make_float4(e4 * inv, e5 * inv, e6 * inv, e7 * inv);
        }

        // ---- v conv (8 outputs per thread), weights via scalar loads
        float va[8];
#pragma unroll
        for (int j = 0; j < 8; j++) va[j] = 0.f;
        const float* xp = xb + pbase + p1;
        for (int c = 0; c < 64; c += 4) {
            float xs0 = xp[(size_t)c * PP];
            float xs1 = xp[(size_t)(c + 1) * PP];
            float xs2 = xp[(size_t)(c + 2) * PP];
            float xs3 = xp[(size_t)(c + 3) * PP];
            const float* w0 = wvu + c * 64;
#pragma unroll
            for (int j = 0; j < 8; j++) {
                va[j] += w0[j] * xs0;
                va[j] += w0[64 + j] * xs1;
                va[j] += w0[128 + j] * xs2;
                va[j] += w0[192 + j] * xs3;
            }
        }
        float4* vt4 = (float4*)(v_tile + p1 * VSTRIDE + o0);
        {
            float4 w;
            w.x = fmaxf(va[0] + bvl[0], 0.f);
            w.y = fmaxf(va[1] + bvl[1], 0.f);
            w.z = fmaxf(va[2] + bvl[2], 0.f);
            w.w = fmaxf(va[3] + bvl[3], 0.f);
            vt4[0] = w;
            w.x = fmaxf(va[4] + bvl[4], 0.f);
            w.y = fmaxf(va[5] + bvl[5], 0.f);
            w.z = fmaxf(va[6] + bvl[6], 0.f);
            w.w = fmaxf(va[7] + bvl[7], 0.f);
            vt4[1] = w;
        }
        __syncthreads();

        // ---- stage 2: accumulate kv contributions
        const int r = pbase % 12;
        {
            int s = l0 - r;
            if (s < 0) s += 12;
            for (int p = s; p < 64; p += 12) {
                float ksv = ks_tile[p * VSTRIDE + (h2 << 3) + x2];
                const float4* vp = (const float4*)(v_tile + p * VSTRIDE + (h2 << 3));
                float4 u0 = vp[0], u1 = vp[1];
                acc[0][0] += ksv * u0.x; acc[0][1] += ksv * u0.y;
                acc[0][2] += ksv * u0.z; acc[0][3] += ksv * u0.w;
                acc[0][4] += ksv * u1.x; acc[0][5] += ksv * u1.y;
                acc[0][6] += ksv * u1.z; acc[0][7] += ksv * u1.w;
            }
        }
        if (has2) {
            int s = l1 - r;
            if (s < 0) s += 12;
            for (int p = s; p < 64; p += 12) {
                float ksv = ks_tile[p * VSTRIDE + (h2 << 3) + x2];
                const float4* vp = (const float4*)(v_tile + p * VSTRIDE + (h2 << 3));
                float4 u0 = vp[0], u1 = vp[1];
                acc[1][0] += ksv * u0.x; acc[1][1] += ksv * u0.y;
                acc[1][2] += ksv * u0.z; acc[1][3] += ksv * u0.w;
                acc[1][4] += ksv * u1.x; acc[1][5] += ksv * u1.y;
                acc[1][6] += ksv * u1.z; acc[1][7] += ksv * u1.w;
            }
        }
        __syncthreads();
    }

    {
        float* kvp = kv + (((size_t)((b * 12 + l0) * 8 + h2)) << 6) + (x2 << 3);
#pragma unroll
        for (int y = 0; y < 8; y++) atomicAdd(kvp + y, acc[0][y]);
    }
    if (has2) {
        float* kvp = kv + (((size_t)((b * 12 + l1) * 8 + h2)) << 6) + (x2 << 3);
#pragma unroll
        for (int y = 0; y < 8; y++) atomicAdd(kvp + y, acc[1][y]);
    }
}

// ---------------------------------------------------------------------------
// Pass B: q conv + softmax + attn(kv) + add v + c conv + affine epilogue
// ---------------------------------------------------------------------------
__global__ __launch_bounds__(256, 8)
void pass_b(const float* __restrict__ x, const float* __restrict__ wqt,
            const float* __restrict__ wvt, const float* __restrict__ wct,
            const float* __restrict__ bq, const float* __restrict__ bv,
            const float* __restrict__ bc, const float* __restrict__ kv,
            const float* __restrict__ wgt, const float* __restrict__ bsa,
            float* __restrict__ out)
{
    __shared__ float y_tile[64 * VSTRIDE];  // [c][p]

    const int t = threadIdx.x;
    const int b = blockIdx.y;
    const int chunk0 = blockIdx.x * CHUNK_B;

    const int p1 = t & 63;
    const int og = t >> 6;
    const int o0 = og << 4;
    // wave-uniform weight base -> scalar loads, no LDS for weights
    const int o0u = __builtin_amdgcn_readfirstlane(o0);
    const float* __restrict__ wqu = wqt + o0u;
    const float* __restrict__ wvu = wvt + o0u;
    const float* __restrict__ wcu = wct + o0u;

    float bql[16], bvl[16], bcl[16];
#pragma unroll
    for (int j = 0; j < 16; j++) {
        bql[j] = bq[o0 + j];
        bvl[j] = bv[o0 + j];
        bcl[j] = bc[o0 + j];
    }

    const float* xb = x + (size_t)(b * 64) * PP;
    float* ob = out + (size_t)(b * 64) * PP;

    for (int tile = 0; tile < NTILES_B; tile++) {
        const int pbase = chunk0 + tile * 64;
        const int pg = pbase + p1;
        const int l = pg % 12;

        // ---- q and v convs
        float qa[16], va[16];
#pragma unroll
        for (int j = 0; j < 16; j++) { qa[j] = 0.f; va[j] = 0.f; }
        const float* xp = xb + pg;
        for (int c = 0; c < 64; c += 4) {
            float xs0 = xp[(size_t)c * PP];
            float xs1 = xp[(size_t)(c + 1) * PP];
            float xs2 = xp[(size_t)(c + 2) * PP];
            float xs3 = xp[(size_t)(c + 3) * PP];
            const float* q0 = wqu + c * 64;
            const float* v0 = wvu + c * 64;
#pragma unroll
            for (int j = 0; j < 16; j++) {
                qa[j] += q0[j] * xs0;       va[j] += v0[j] * xs0;
                qa[j] += q0[64 + j] * xs1;  va[j] += v0[64 + j] * xs1;
                qa[j] += q0[128 + j] * xs2; va[j] += v0[128 + j] * xs2;
                qa[j] += q0[192 + j] * xs3; va[j] += v0[192 + j] * xs3;
            }
        }
#pragma unroll
        for (int j = 0; j < 16; j++) {
            qa[j] = fmaxf(qa[j] + bql[j], 0.f) * SCALE;  // relu then *scale
            va[j] = fmaxf(va[j] + bvl[j], 0.f);
        }

        // ---- softmax over DK=8 per head (2 heads per thread, in-register)
#pragma unroll
        for (int hh = 0; hh < 2; hh++) {
            float* qh = qa + hh * 8;
            float m = fmaxf(fmaxf(fmaxf(qh[0], qh[1]), fmaxf(qh[2], qh[3])),
                            fmaxf(fmaxf(qh[4], qh[5]), fmaxf(qh[6], qh[7])));
            float s = 0.f;
#pragma unroll
            for (int xk = 0; xk < 8; xk++) { qh[xk] = __expf(qh[xk] - m); s += qh[xk]; }
            float inv = 1.0f / s;
#pragma unroll
            for (int xk = 0; xk < 8; xk++) qh[xk] *= inv;
        }

        // ---- attn: y = q_sm @ kv + v   (attn_dyn == v since softmax rows sum to 1)
#pragma unroll
        for (int hh = 0; hh < 2; hh++) {
            const int h = og * 2 + hh;
            const float* kvp = kv + (((size_t)((b * 12 + l) * 8 + h)) << 6);
            float yv[8];
#pragma unroll
            for (int y = 0; y < 8; y++) yv[y] = va[hh * 8 + y];
#pragma unroll
            for (int xk = 0; xk < 8; xk++) {
                float qv = qa[hh * 8 + xk];
                const float4* kp = (const float4*)(kvp + (xk << 3));
                float4 k0 = kp[0], k1 = kp[1];
                yv[0] += qv * k0.x; yv[1] += qv * k0.y;
                yv[2] += qv * k0.z; yv[3] += qv * k0.w;
                yv[4] += qv * k1.x; yv[5] += qv * k1.y;
                yv[6] += qv * k1.z; yv[7] += qv * k1.w;
            }
#pragma unroll
            for (int y = 0; y < 8; y++)
                y_tile[(o0 + hh * 8 + y) * VSTRIDE + p1] = yv[y];
        }
        __syncthreads();

        // ---- output conv + epilogue: out = relu(Wc y + bc) * (wgt + 1) + bias
        float ca[16];
#pragma unroll
        for (int j = 0; j < 16; j++) ca[j] = 0.f;
        for (int c = 0; c < 64; c += 4) {
            float y0 = y_tile[c * VSTRIDE + p1];
            float y1 = y_tile[(c + 1) * VSTRIDE + p1];
            float y2 = y_tile[(c + 2) * VSTRIDE + p1];
            float y3 = y_tile[(c + 3) * VSTRIDE + p1];
            const float* w0 = wcu + c * 64;
#pragma unroll
            for (int j = 0; j < 16; j++) {
                ca[j] += w0[j] * y0;
                ca[j] += w0[64 + j] * y1;
                ca[j] += w0[128 + j] * y2;
                ca[j] += w0[192 + j] * y3;
            }
        }
#pragma unroll
        for (int j = 0; j < 16; j++) {
            float yc = fmaxf(ca[j] + bcl[j], 0.f);
            size_t oi = (size_t)(o0 + j) * PP + pg;
            ob[oi] = yc * (wgt[oi] + 1.0f) + bsa[oi];
        }
        __syncthreads();
    }
}

extern "C" void kernel_launch(void* const* d_in, const int* in_sizes, int n_in,
                              void* d_out, int out_size, void* d_ws, size_t ws_size,
                              hipStream_t stream) {
    const float* x   = (const float*)d_in[0];
    const float* wq  = (const float*)d_in[1];
    const float* bq  = (const float*)d_in[2];
    const float* wv  = (const float*)d_in[3];
    const float* bv  = (const float*)d_in[4];
    const float* wc  = (const float*)d_in[5];
    const float* bc  = (const float*)d_in[6];
    const float* mem = (const float*)d_in[7];
    const float* wgt = (const float*)d_in[8];
    const float* bsa = (const float*)d_in[9];
    // d_in[10], d_in[11] (nv1, nv2) are mathematically dead:
    // row-sums of a softmax over its own axis are exactly 1 -> attn_dyn = v5.
    float* outp = (float*)d_out;

    float* kvw = (float*)d_ws;                      // [B][L][H][8][8] = 786432 bytes
    float* wt  = (float*)d_ws + (size_t)BB * LL * HH * 64;  // 3 x 4096 floats (48 KB)
    hipMemsetAsync(kvw, 0, (size_t)BB * LL * HH * 64 * sizeof(float), stream);

    prep<<<16, 256, 0, stream>>>(wq, wv, wc, wt);

    dim3 grid_a(NCHUNK_A, BB);
    pass_a<<<grid_a, 512, 0, stream>>>(x, wt + 4096, bv, mem, kvw);
    dim3 grid_b(NCHUNK_B, BB);
    pass_b<<<grid_b, 256, 0, stream>>>(x, wt, wt + 4096, wt + 8192,
                                       bq, bv, bc, kvw, wgt, bsa, outp);
}

// Round 3
// 1915.341 us; speedup vs baseline: 1.6886x; 1.6886x over previous
//
#include <hip/hip_runtime.h>
#include <math.h>

#define BB 32
#define DD 64
#define HH 8
#define NNN 4096
#define LL 12
#define PP (NNN * LL)            // 49152 positions per (b, channel)

// pass_a geometry: 512-thread blocks, 64-pos tiles, exact-fill grid (4 blocks/CU)
#define NTILES_A 24
#define CHUNK_A (64 * NTILES_A)  // 1536
#define NCHUNK_A (PP / CHUNK_A)  // 32

// pass_b geometry: 256-thread blocks, 64-pos tiles, 8 blocks/CU resident
#define NTILES_B 12
#define CHUNK_B (64 * NTILES_B)  // 768
#define NCHUNK_B (PP / CHUNK_B)  // 64

#define VSTRIDE 68               // LDS row stride (floats): 16B-aligned rows, bank-skewed
#define SCALE 0.35355339059327373f

// ---------------------------------------------------------------------------
// prep: transpose the three 64x64 weight matrices into [c][o] layout in ws.
// Weight reads in the main passes are wave-uniform -> served via scalar path.
// ---------------------------------------------------------------------------
__global__ void prep(const float* __restrict__ wq, const float* __restrict__ wv,
                     const float* __restrict__ wc, float* __restrict__ wt)
{
    const int i = blockIdx.x * 256 + threadIdx.x;  // i = o*64 + c, 0..4095
    const int o = i >> 6, c = i & 63;
    wt[c * 64 + o]        = wq[i];
    wt[4096 + c * 64 + o] = wv[i];
    wt[8192 + c * 64 + o] = wc[i];
}

// ---------------------------------------------------------------------------
// prep_ksm: key-softmax depends only on (h,l,n) but was being recomputed for
// every batch with scattered 32B loads.  Compute once, store p-major:
//   ksm_t[p][h][x],  p = n*12 + l   (so a pass_a tile reads one 16 KB slab).
// ---------------------------------------------------------------------------
__global__ void prep_ksm(const float* __restrict__ mem, float* __restrict__ ksm)
{
    const int g = blockIdx.x * 256 + threadIdx.x;  // (p,h) job, 0..393215
    const int p = g >> 3, h = g & 7;
    const int n = p / 12, l = p - n * 12;
    const float4* mp = (const float4*)(mem + (((size_t)(h * 12 + l) * NNN + n) << 3));
    float4 a0 = mp[0], a1 = mp[1];
    float v0 = a0.x * SCALE, v1 = a0.y * SCALE, v2 = a0.z * SCALE, v3 = a0.w * SCALE;
    float v4 = a1.x * SCALE, v5 = a1.y * SCALE, v6 = a1.z * SCALE, v7 = a1.w * SCALE;
    float m = fmaxf(fmaxf(fmaxf(v0, v1), fmaxf(v2, v3)),
                    fmaxf(fmaxf(v4, v5), fmaxf(v6, v7)));
    float e0 = __expf(v0 - m), e1 = __expf(v1 - m), e2 = __expf(v2 - m), e3 = __expf(v3 - m);
    float e4 = __expf(v4 - m), e5 = __expf(v5 - m), e6 = __expf(v6 - m), e7 = __expf(v7 - m);
    float inv = 1.0f / (e0 + e1 + e2 + e3 + e4 + e5 + e6 + e7);
    float4* op = (float4*)(ksm + ((size_t)g << 3));
    op[0] = make_float4(e0 * inv, e1 * inv, e2 * inv, e3 * inv);
    op[1] = make_float4(e4 * inv, e5 * inv, e6 * inv, e7 * inv);
}

// ---------------------------------------------------------------------------
// Pass A: kv[b,l,h,x,y] = sum_n ksm[h,l,n,x] * relu(Wv x + bv)[h*8+y]
// 512 threads: stage 1 = 8 channels/thread (wave-uniform og), stage 2 = 768
// (l,h,x) jobs mapped {t, 512+t}.  4 blocks/CU x 8 waves = 32 waves/CU.
// ---------------------------------------------------------------------------
__global__ __launch_bounds__(512, 8)
void pass_a(const float* __restrict__ x, const float* __restrict__ wvt,
            const float* __restrict__ bv, const float* __restrict__ mem,
            const float* __restrict__ ksm,  // p-major key-softmax, or null
            float* __restrict__ kv)
{
    __shared__ float v_tile[64 * VSTRIDE];   // [p][o]
    __shared__ float ks_tile[64 * VSTRIDE];  // [p][h*8+x]

    const int t = threadIdx.x;
    const int b = blockIdx.y;
    const int chunk0 = blockIdx.x * CHUNK_A;

    // stage-1 mapping: p1 = position-in-tile, og = 8-channel group (wave-uniform)
    const int p1 = t & 63;
    const int og = t >> 6;           // 0..7, constant within a 64-lane wave
    const int o0 = og << 3;
    const int o0u = __builtin_amdgcn_readfirstlane(o0);
    const float* __restrict__ wvu = wvt + o0u;

    float bvl[8];
#pragma unroll
    for (int j = 0; j < 8; j++) bvl[j] = bv[o0 + j];

    // stage-2 mapping: job j in 0..767 -> l = j>>6, h = (j>>3)&7, x = j&7
    // thread t owns job t, and job 512+t when t < 256
    const int h2 = (t >> 3) & 7;
    const int x2 = t & 7;
    const int l0 = t >> 6;           // 0..7, wave-uniform
    const int l1 = 8 + (t >> 6);     // 8..11 (valid only for t < 256)
    const bool has2 = (t < 256);

    float acc[2][8];
#pragma unroll
    for (int q = 0; q < 2; q++)
#pragma unroll
        for (int y = 0; y < 8; y++) acc[q][y] = 0.f;

    const float* xb = x + (size_t)(b * 64) * PP;

    for (int tile = 0; tile < NTILES_A; tile++) {
        const int pbase = chunk0 + tile * 64;

        // ---- key-softmax staging: 64 pos x 8 heads = 512 jobs, 1 per thread
        if (ksm) {
            // contiguous 16 KB slab: lane t reads ksm[(pbase + t>>3)*64 + (t&7)*8]
            const int pos = t >> 3, h = t & 7;
            const float4* kg = (const float4*)(ksm + (((size_t)(pbase + pos)) << 6) + (h << 3));
            float4 a0 = kg[0], a1 = kg[1];
            float4* kp = (float4*)(ks_tile + pos * VSTRIDE + (h << 3));
            kp[0] = a0; kp[1] = a1;
        } else {
            int pos = t >> 3, h = t & 7;
            int pg = pbase + pos;
            int n = pg / 12;
            int l = pg - n * 12;
            const float4* mp = (const float4*)(mem + (((size_t)(h * 12 + l) * NNN + n) << 3));
            float4 a0 = mp[0], a1 = mp[1];
            float v0 = a0.x * SCALE, v1 = a0.y * SCALE, v2 = a0.z * SCALE, v3 = a0.w * SCALE;
            float v4 = a1.x * SCALE, v5 = a1.y * SCALE, v6 = a1.z * SCALE, v7 = a1.w * SCALE;
            float m = fmaxf(fmaxf(fmaxf(v0, v1), fmaxf(v2, v3)),
                            fmaxf(fmaxf(v4, v5), fmaxf(v6, v7)));
            float e0 = __expf(v0 - m), e1 = __expf(v1 - m), e2 = __expf(v2 - m), e3 = __expf(v3 - m);
            float e4 = __expf(v4 - m), e5 = __expf(v5 - m), e6 = __expf(v6 - m), e7 = __expf(v7 - m);
            float inv = 1.0f / (e0 + e1 + e2 + e3 + e4 + e5 + e6 + e7);
            float4* kp = (float4*)(ks_tile + pos * VSTRIDE + (h << 3));
            kp[0] = make_float4(e0 * inv, e1 * inv, e2 * inv, e3 * inv);
            kp[1] = make_float4(e4 * inv, e5 * inv, e6 * inv, e7 * inv);
        }

        // ---- v conv (8 outputs per thread), weights via scalar loads
        float va[8];
#pragma unroll
        for (int j = 0; j < 8; j++) va[j] = 0.f;
        const float* xp = xb + pbase + p1;
        for (int c = 0; c < 64; c += 4) {
            float xs0 = xp[(size_t)c * PP];
            float xs1 = xp[(size_t)(c + 1) * PP];
            float xs2 = xp[(size_t)(c + 2) * PP];
            float xs3 = xp[(size_t)(c + 3) * PP];
            const float* w0 = wvu + c * 64;
#pragma unroll
            for (int j = 0; j < 8; j++) {
                va[j] += w0[j] * xs0;
                va[j] += w0[64 + j] * xs1;
                va[j] += w0[128 + j] * xs2;
                va[j] += w0[192 + j] * xs3;
            }
        }
        float4* vt4 = (float4*)(v_tile + p1 * VSTRIDE + o0);
        {
            float4 w;
            w.x = fmaxf(va[0] + bvl[0], 0.f);
            w.y = fmaxf(va[1] + bvl[1], 0.f);
            w.z = fmaxf(va[2] + bvl[2], 0.f);
            w.w = fmaxf(va[3] + bvl[3], 0.f);
            vt4[0] = w;
            w.x = fmaxf(va[4] + bvl[4], 0.f);
            w.y = fmaxf(va[5] + bvl[5], 0.f);
            w.z = fmaxf(va[6] + bvl[6], 0.f);
            w.w = fmaxf(va[7] + bvl[7], 0.f);
            vt4[1] = w;
        }
        __syncthreads();

        // ---- stage 2: accumulate kv contributions
        const int r = pbase % 12;
        {
            int s = l0 - r;
            if (s < 0) s += 12;
            for (int p = s; p < 64; p += 12) {
                float ksv = ks_tile[p * VSTRIDE + (h2 << 3) + x2];
                const float4* vp = (const float4*)(v_tile + p * VSTRIDE + (h2 << 3));
                float4 u0 = vp[0], u1 = vp[1];
                acc[0][0] += ksv * u0.x; acc[0][1] += ksv * u0.y;
                acc[0][2] += ksv * u0.z; acc[0][3] += ksv * u0.w;
                acc[0][4] += ksv * u1.x; acc[0][5] += ksv * u1.y;
                acc[0][6] += ksv * u1.z; acc[0][7] += ksv * u1.w;
            }
        }
        if (has2) {
            int s = l1 - r;
            if (s < 0) s += 12;
            for (int p = s; p < 64; p += 12) {
                float ksv = ks_tile[p * VSTRIDE + (h2 << 3) + x2];
                const float4* vp = (const float4*)(v_tile + p * VSTRIDE + (h2 << 3));
                float4 u0 = vp[0], u1 = vp[1];
                acc[1][0] += ksv * u0.x; acc[1][1] += ksv * u0.y;
                acc[1][2] += ksv * u0.z; acc[1][3] += ksv * u0.w;
                acc[1][4] += ksv * u1.x; acc[1][5] += ksv * u1.y;
                acc[1][6] += ksv * u1.z; acc[1][7] += ksv * u1.w;
            }
        }
        __syncthreads();
    }

    {
        float* kvp = kv + (((size_t)((b * 12 + l0) * 8 + h2)) << 6) + (x2 << 3);
#pragma unroll
        for (int y = 0; y < 8; y++) atomicAdd(kvp + y, acc[0][y]);
    }
    if (has2) {
        float* kvp = kv + (((size_t)((b * 12 + l1) * 8 + h2)) << 6) + (x2 << 3);
#pragma unroll
        for (int y = 0; y < 8; y++) atomicAdd(kvp + y, acc[1][y]);
    }
}

// ---------------------------------------------------------------------------
// Pass B: q conv + softmax + attn(kv) + add v + c conv + affine epilogue
// NOTE: __launch_bounds__(256,4) — round 2 proved (256,8) squeezes VGPR to 32
// and spills ~780 MB to scratch.  At 64 VGPR the HW already allows 8 waves/EU;
// the doubled grid (NCHUNK_B=64 -> 2048 blocks = 8 blocks/CU) supplies them.
// ---------------------------------------------------------------------------
__global__ __launch_bounds__(256, 4)
void pass_b(const float* __restrict__ x, const float* __restrict__ wqt,
            const float* __restrict__ wvt, const float* __restrict__ wct,
            const float* __restrict__ bq, const float* __restrict__ bv,
            const float* __restrict__ bc, const float* __restrict__ kv,
            const float* __restrict__ wgt, const float* __restrict__ bsa,
            float* __restrict__ out)
{
    __shared__ float y_tile[64 * VSTRIDE];  // [c][p]

    const int t = threadIdx.x;
    const int b = blockIdx.y;
    const int chunk0 = blockIdx.x * CHUNK_B;

    const int p1 = t & 63;
    const int og = t >> 6;
    const int o0 = og << 4;
    // wave-uniform weight base -> scalar loads, no LDS for weights
    const int o0u = __builtin_amdgcn_readfirstlane(o0);
    const float* __restrict__ wqu = wqt + o0u;
    const float* __restrict__ wvu = wvt + o0u;
    const float* __restrict__ wcu = wct + o0u;

    float bql[16], bvl[16], bcl[16];
#pragma unroll
    for (int j = 0; j < 16; j++) {
        bql[j] = bq[o0 + j];
        bvl[j] = bv[o0 + j];
        bcl[j] = bc[o0 + j];
    }

    const float* xb = x + (size_t)(b * 64) * PP;
    float* ob = out + (size_t)(b * 64) * PP;

    for (int tile = 0; tile < NTILES_B; tile++) {
        const int pbase = chunk0 + tile * 64;
        const int pg = pbase + p1;
        const int l = pg % 12;

        // ---- q and v convs
        float qa[16], va[16];
#pragma unroll
        for (int j = 0; j < 16; j++) { qa[j] = 0.f; va[j] = 0.f; }
        const float* xp = xb + pg;
        for (int c = 0; c < 64; c += 4) {
            float xs0 = xp[(size_t)c * PP];
            float xs1 = xp[(size_t)(c + 1) * PP];
            float xs2 = xp[(size_t)(c + 2) * PP];
            float xs3 = xp[(size_t)(c + 3) * PP];
            const float* q0 = wqu + c * 64;
            const float* v0 = wvu + c * 64;
#pragma unroll
            for (int j = 0; j < 16; j++) {
                qa[j] += q0[j] * xs0;       va[j] += v0[j] * xs0;
                qa[j] += q0[64 + j] * xs1;  va[j] += v0[64 + j] * xs1;
                qa[j] += q0[128 + j] * xs2; va[j] += v0[128 + j] * xs2;
                qa[j] += q0[192 + j] * xs3; va[j] += v0[192 + j] * xs3;
            }
        }
#pragma unroll
        for (int j = 0; j < 16; j++) {
            qa[j] = fmaxf(qa[j] + bql[j], 0.f) * SCALE;  // relu then *scale
            va[j] = fmaxf(va[j] + bvl[j], 0.f);
        }

        // ---- softmax over DK=8 per head (2 heads per thread, in-register)
#pragma unroll
        for (int hh = 0; hh < 2; hh++) {
            float* qh = qa + hh * 8;
            float m = fmaxf(fmaxf(fmaxf(qh[0], qh[1]), fmaxf(qh[2], qh[3])),
                            fmaxf(fmaxf(qh[4], qh[5]), fmaxf(qh[6], qh[7])));
            float s = 0.f;
#pragma unroll
            for (int xk = 0; xk < 8; xk++) { qh[xk] = __expf(qh[xk] - m); s += qh[xk]; }
            float inv = 1.0f / s;
#pragma unroll
            for (int xk = 0; xk < 8; xk++) qh[xk] *= inv;
        }

        // ---- attn: y = q_sm @ kv + v   (attn_dyn == v since softmax rows sum to 1)
#pragma unroll
        for (int hh = 0; hh < 2; hh++) {
            const int h = og * 2 + hh;
            const float* kvp = kv + (((size_t)((b * 12 + l) * 8 + h)) << 6);
            float yv[8];
#pragma unroll
            for (int y = 0; y < 8; y++) yv[y] = va[hh * 8 + y];
#pragma unroll
            for (int xk = 0; xk < 8; xk++) {
                float qv = qa[hh * 8 + xk];
                const float4* kp = (const float4*)(kvp + (xk << 3));
                float4 k0 = kp[0], k1 = kp[1];
                yv[0] += qv * k0.x; yv[1] += qv * k0.y;
                yv[2] += qv * k0.z; yv[3] += qv * k0.w;
                yv[4] += qv * k1.x; yv[5] += qv * k1.y;
                yv[6] += qv * k1.z; yv[7] += qv * k1.w;
            }
#pragma unroll
            for (int y = 0; y < 8; y++)
                y_tile[(o0 + hh * 8 + y) * VSTRIDE + p1] = yv[y];
        }
        __syncthreads();

        // ---- output conv + epilogue: out = relu(Wc y + bc) * (wgt + 1) + bias
        float ca[16];
#pragma unroll
        for (int j = 0; j < 16; j++) ca[j] = 0.f;
        for (int c = 0; c < 64; c += 4) {
            float y0 = y_tile[c * VSTRIDE + p1];
            float y1 = y_tile[(c + 1) * VSTRIDE + p1];
            float y2 = y_tile[(c + 2) * VSTRIDE + p1];
            float y3 = y_tile[(c + 3) * VSTRIDE + p1];
            const float* w0 = wcu + c * 64;
#pragma unroll
            for (int j = 0; j < 16; j++) {
                ca[j] += w0[j] * y0;
                ca[j] += w0[64 + j] * y1;
                ca[j] += w0[128 + j] * y2;
                ca[j] += w0[192 + j] * y3;
            }
        }
#pragma unroll
        for (int j = 0; j < 16; j++) {
            float yc = fmaxf(ca[j] + bcl[j], 0.f);
            size_t oi = (size_t)(o0 + j) * PP + pg;
            ob[oi] = yc * (wgt[oi] + 1.0f) + bsa[oi];
        }
        __syncthreads();
    }
}

extern "C" void kernel_launch(void* const* d_in, const int* in_sizes, int n_in,
                              void* d_out, int out_size, void* d_ws, size_t ws_size,
                              hipStream_t stream) {
    const float* x   = (const float*)d_in[0];
    const float* wq  = (const float*)d_in[1];
    const float* bq  = (const float*)d_in[2];
    const float* wv  = (const float*)d_in[3];
    const float* bv  = (const float*)d_in[4];
    const float* wc  = (const float*)d_in[5];
    const float* bc  = (const float*)d_in[6];
    const float* mem = (const float*)d_in[7];
    const float* wgt = (const float*)d_in[8];
    const float* bsa = (const float*)d_in[9];
    // d_in[10], d_in[11] (nv1, nv2) are mathematically dead:
    // row-sums of a softmax over its own axis are exactly 1 -> attn_dyn = v5.
    float* outp = (float*)d_out;

    const size_t kv_floats  = (size_t)BB * LL * HH * 64;   // 196608
    const size_t wt_floats  = 3 * 4096;                    // 12288
    const size_t ksm_floats = (size_t)PP * 64;             // 3145728 (12.6 MB)

    float* kvw = (float*)d_ws;
    float* wt  = kvw + kv_floats;
    float* ksm = wt + wt_floats;
    const bool have_ksm =
        ws_size >= (kv_floats + wt_floats + ksm_floats) * sizeof(float);

    hipMemsetAsync(kvw, 0, kv_floats * sizeof(float), stream);

    prep<<<16, 256, 0, stream>>>(wq, wv, wc, wt);
    if (have_ksm) {
        prep_ksm<<<(PP * 8) / 256, 256, 0, stream>>>(mem, ksm);
    }

    dim3 grid_a(NCHUNK_A, BB);
    pass_a<<<grid_a, 512, 0, stream>>>(x, wt + 4096, bv, mem,
                                       have_ksm ? ksm : nullptr, kvw);
    dim3 grid_b(NCHUNK_B, BB);
    pass_b<<<grid_b, 256, 0, stream>>>(x, wt, wt + 4096, wt + 8192,
                                       bq, bv, bc, kvw, wgt, bsa, outp);
}